// Round 1
// baseline (305.018 us; speedup 1.0000x reference)
//
#include <hip/hip_runtime.h>
#include <hip/hip_bf16.h>

// Problem constants (fixed by setup_inputs)
// B=16, N=64, T=128, D=8, N_EMB=64, N_H=128, BN=1024, F_in=128, gates=512

typedef _Float16 half8 __attribute__((ext_vector_type(8)));
typedef float f32x4 __attribute__((ext_vector_type(4)));

__device__ __forceinline__ float sigmoidf_(float x){ return 1.0f/(1.0f + __expf(-x)); }
__device__ __forceinline__ float tanhf_(float x){ return 1.0f - 2.0f/(__expf(2.0f*x) + 1.0f); }

// ---------------------------------------------------------------------------
// Kernel 1: repack W_ih (512x128) and W_hh (512x128) into f16 MFMA B-fragment
// order. Layout: wfrag[w][i][lane][e], i = src*16 + kk*4 + cti  (32 frags/wave)
//   j = 16*w + 128*cti + (lane&15)      (gate column; cti IS the gate index)
//   k = 32*kk + 8*(lane>>4) + e         (K position within src block)
// ---------------------------------------------------------------------------
__global__ __launch_bounds__(256) void prep_kernel(const float* __restrict__ W_ih,
                                                   const float* __restrict__ W_hh,
                                                   _Float16* __restrict__ wfrag){
  int gid = blockIdx.x*256 + threadIdx.x;   // [0, 16384)
  int w    = gid >> 11;        // 0..7
  int i    = (gid >> 6) & 31;  // 0..31
  int lane = gid & 63;
  int src = i >> 4, kk = (i >> 2) & 3, cti = i & 3;
  int j = 16*w + 128*cti + (lane & 15);
  int kbase = 32*kk + 8*(lane >> 4);
  const float* W = src ? W_hh : W_ih;
  _Float16* dst = wfrag + (size_t)(((w*32 + i)*64 + lane) * 8);
  #pragma unroll
  for (int e = 0; e < 8; e++) dst[e] = (_Float16)W[j*128 + kbase + e];
}

// ---------------------------------------------------------------------------
// Kernel 2: GCN. One block per (b,t). Writes feat[t][b*64+n][f] as f16.
// ---------------------------------------------------------------------------
__global__ __launch_bounds__(256) void gcn_kernel(const float* __restrict__ x,
    const float* __restrict__ Wc, const float* __restrict__ bc,
    const float* __restrict__ Ws, const float* __restrict__ bs,
    _Float16* __restrict__ feat){
  int blk = blockIdx.x;          // 0..2047
  int t = blk & 127, b = blk >> 7;
  int tid = threadIdx.x;
  __shared__ float xs[64][9];
  __shared__ float As[64][65];
  __shared__ float ys[64][9];
  __shared__ float invr[64];
  __shared__ float Wcs[64][8], Wss[64][8];
  __shared__ float bcs[64], bss[64];

  for (int idx = tid; idx < 512; idx += 256){
    int n = idx >> 3, d = idx & 7;
    xs[n][d]  = x[((size_t)(b*64 + n)*128 + t)*8 + d];
    Wcs[n][d] = Wc[idx];
    Wss[n][d] = Ws[idx];
  }
  if (tid < 64){ bcs[tid] = bc[tid]; bss[tid] = bs[tid]; }
  __syncthreads();

  // pairwise inverse distances (diag = 0)
  for (int p = tid; p < 4096; p += 256){
    int m = p >> 6, n = p & 63;
    float d2 = 0.f;
    #pragma unroll
    for (int d = 0; d < 8; d++){ float df = xs[m][d] - xs[n][d]; d2 += df*df; }
    As[m][n] = (m == n) ? 0.f : 1.0f/(sqrtf(d2) + 1e-20f);
  }
  __syncthreads();

  if (tid < 64){
    float s = 0.f;
    #pragma unroll
    for (int m = 0; m < 64; m++) s += As[tid][m];
    invr[tid] = 1.0f / fmaxf(s, 1e-12f);
  }
  __syncthreads();

  // y = rownorm(A) @ x
  for (int idx = tid; idx < 512; idx += 256){
    int s = idx >> 3, d = idx & 7;
    float acc = 0.f;
    #pragma unroll
    for (int m = 0; m < 64; m++) acc += As[s][m]*xs[m][d];
    ys[s][d] = acc * invr[s];
  }
  __syncthreads();

  // outputs: f<64 skip-proj of x, f>=64 proj of y; SELU; f16 store
  int n = tid >> 2, q = tid & 3;
  size_t obase = ((size_t)t*1024 + (size_t)b*64 + n)*128;
  #pragma unroll
  for (int ii = 0; ii < 32; ii++){
    int f = q*32 + ii;
    float v;
    if (f < 64){
      v = bss[f];
      #pragma unroll
      for (int d = 0; d < 8; d++) v += xs[n][d]*Wss[f][d];
    } else {
      int fc = f - 64;
      v = bcs[fc];
      #pragma unroll
      for (int d = 0; d < 8; d++) v += ys[n][d]*Wcs[fc][d];
    }
    v = (v > 0.f) ? 1.0507009873554805f*v
                  : 1.7580993408473766f*(__expf(v) - 1.0f);  // scale*alpha
    feat[obase + f] = (_Float16)v;
  }
}

// ---------------------------------------------------------------------------
// Kernel 3: persistent LSTM. 64 blocks x 512 thr (8 waves). Block owns samples
// blk*16..+15. Weights (both GEMMs, K=256) live in VGPRs as B-fragments.
// Wave w owns gate columns j = 16w..16w+15 for all 4 gates -> in-register cell.
// ---------------------------------------------------------------------------
__global__ __launch_bounds__(512, 2) void lstm_kernel(
    const _Float16* __restrict__ wfrag, const _Float16* __restrict__ feat,
    const float* __restrict__ b_ih, const float* __restrict__ b_hh,
    float* __restrict__ out){
  int tid = threadIdx.x;
  int w = tid >> 6, l = tid & 63;
  int blk = blockIdx.x;            // 0..63
  int row = l & 15, kq = l >> 4;
  __shared__ _Float16 h_lds[16*136];   // [sample][hidden], stride 136 (2-way banks)

  // load this wave's 32 B-fragments (coalesced: lane-contiguous layout)
  half8 bf[32];
  const _Float16* wb = wfrag + (size_t)w*(32*64*8);
  #pragma unroll
  for (int i = 0; i < 32; i++)
    bf[i] = *(const half8*)(wb + (size_t)(i*64 + l)*8);

  float bias[4];
  #pragma unroll
  for (int cti = 0; cti < 4; cti++){
    int j = 16*w + 128*cti + row;
    bias[cti] = b_ih[j] + b_hh[j];
  }

  for (int idx = tid; idx < 16*136; idx += 512) h_lds[idx] = (_Float16)0.f;

  float cc[4] = {0.f, 0.f, 0.f, 0.f};

  const size_t sbase = ((size_t)blk*16 + row)*128 + 8*kq;  // per-lane feat base
  half8 xa[4];
  #pragma unroll
  for (int kk = 0; kk < 4; kk++)
    xa[kk] = *(const half8*)(feat + sbase + 32*kk);        // t = 0
  __syncthreads();

  const int hoff = row*136 + 8*kq;

  for (int t = 0; t < 128; ++t){
    f32x4 acc[4];
    #pragma unroll
    for (int c4 = 0; c4 < 4; c4++)
      acc[c4] = (f32x4){bias[c4], bias[c4], bias[c4], bias[c4]};

    // prefetch next step's x fragments (latency hidden under MFMAs)
    half8 xn[4];
    size_t nb = (size_t)((t < 127) ? t + 1 : 127)*131072 + sbase;
    #pragma unroll
    for (int kk = 0; kk < 4; kk++)
      xn[kk] = *(const half8*)(feat + nb + 32*kk);

    // input-GEMM part (x frags loaded previous iteration)
    #pragma unroll
    for (int kk = 0; kk < 4; kk++){
      #pragma unroll
      for (int cti = 0; cti < 4; cti++)
        acc[cti] = __builtin_amdgcn_mfma_f32_16x16x32_f16(xa[kk], bf[kk*4 + cti], acc[cti], 0, 0, 0);
    }
    // recurrent part (h from LDS)
    #pragma unroll
    for (int kk = 0; kk < 4; kk++){
      half8 ha = *(const half8*)(h_lds + hoff + 32*kk);
      #pragma unroll
      for (int cti = 0; cti < 4; cti++)
        acc[cti] = __builtin_amdgcn_mfma_f32_16x16x32_f16(ha, bf[(4 + kk)*4 + cti], acc[cti], 0, 0, 0);
    }
    __syncthreads();   // all waves done reading h_lds

    // in-register cell update: lane holds i,f,g,o for (s = 4*kq+e, j = 16w+row)
    #pragma unroll
    for (int e = 0; e < 4; e++){
      float gi = acc[0][e], gf = acc[1][e], gg = acc[2][e], go = acc[3][e];
      float c = sigmoidf_(gf)*cc[e] + sigmoidf_(gi)*tanhf_(gg);
      cc[e] = c;
      float h = sigmoidf_(go)*tanhf_(c);
      h_lds[(4*kq + e)*136 + 16*w + row] = (_Float16)h;
      if (t == 127)
        out[((size_t)blk*16 + 4*kq + e)*128 + 16*w + row] = h;
    }
    __syncthreads();   // h_lds updated for next step

    #pragma unroll
    for (int kk = 0; kk < 4; kk++) xa[kk] = xn[kk];
  }
}

// ---------------------------------------------------------------------------
extern "C" void kernel_launch(void* const* d_in, const int* in_sizes, int n_in,
                              void* d_out, int out_size, void* d_ws, size_t ws_size,
                              hipStream_t stream) {
  const float* x    = (const float*)d_in[0];
  // d_in[1] rel_rec, d_in[2] rel_send: fully-connected structure is fixed; unused
  const float* Wc   = (const float*)d_in[3];
  const float* bc   = (const float*)d_in[4];
  const float* Ws   = (const float*)d_in[5];
  const float* bs   = (const float*)d_in[6];
  const float* W_ih = (const float*)d_in[7];
  const float* W_hh = (const float*)d_in[8];
  const float* b_ih = (const float*)d_in[9];
  const float* b_hh = (const float*)d_in[10];
  float* out = (float*)d_out;

  // ws layout: [0,256KB) weight fragments f16; [256KB, +33.5MB) feat f16
  _Float16* wfrag = (_Float16*)d_ws;
  _Float16* feat  = (_Float16*)((char*)d_ws + 262144);

  prep_kernel<<<64, 256, 0, stream>>>(W_ih, W_hh, wfrag);
  gcn_kernel<<<2048, 256, 0, stream>>>(x, Wc, bc, Ws, bs, feat);
  lstm_kernel<<<64, 512, 0, stream>>>(wfrag, feat, b_ih, b_hh, out);
}

// Round 2
// 179.769 us; speedup vs baseline: 1.6967x; 1.6967x over previous
//
#include <hip/hip_runtime.h>
#include <hip/hip_bf16.h>

// Problem constants (fixed by setup_inputs)
// B=16, N=64, T=128, D=8, N_EMB=64, N_H=128, BN=1024, F_in=128, gates=512

typedef _Float16 half8 __attribute__((ext_vector_type(8)));
typedef float f32x4 __attribute__((ext_vector_type(4)));

__device__ __forceinline__ float rcp_(float x){ return __builtin_amdgcn_rcpf(x); }
__device__ __forceinline__ float sigmoidf_(float x){ return rcp_(1.0f + __expf(-x)); }
__device__ __forceinline__ float tanhf_(float x){ return fmaf(-2.0f, rcp_(1.0f + __expf(2.0f*x)), 1.0f); }

// ---------------------------------------------------------------------------
// Kernel 1: repack W_ih (512x128) and W_hh (512x128) into f16 MFMA B-fragment
// order. Layout: wfrag[w][i][lane][e], i = src*16 + kk*4 + cti  (32 frags/wave)
//   j = 16*w + 128*cti + (lane&15)      (gate column; cti IS the gate index)
//   k = 32*kk + 8*(lane>>4) + e         (K position within src block)
// ---------------------------------------------------------------------------
__global__ __launch_bounds__(256) void prep_kernel(const float* __restrict__ W_ih,
                                                   const float* __restrict__ W_hh,
                                                   _Float16* __restrict__ wfrag){
  int gid = blockIdx.x*256 + threadIdx.x;   // [0, 16384)
  int w    = gid >> 11;        // 0..7
  int i    = (gid >> 6) & 31;  // 0..31
  int lane = gid & 63;
  int src = i >> 4, kk = (i >> 2) & 3, cti = i & 3;
  int j = 16*w + 128*cti + (lane & 15);
  int kbase = 32*kk + 8*(lane >> 4);
  const float* W = src ? W_hh : W_ih;
  _Float16* dst = wfrag + (size_t)(((w*32 + i)*64 + lane) * 8);
  #pragma unroll
  for (int e = 0; e < 8; e++) dst[e] = (_Float16)W[j*128 + kbase + e];
}

// ---------------------------------------------------------------------------
// Kernel 2: GCN. One block per (b,t). Writes feat[t][b*64+n][f] as f16.
// ---------------------------------------------------------------------------
__global__ __launch_bounds__(256) void gcn_kernel(const float* __restrict__ x,
    const float* __restrict__ Wc, const float* __restrict__ bc,
    const float* __restrict__ Ws, const float* __restrict__ bs,
    _Float16* __restrict__ feat){
  int blk = blockIdx.x;          // 0..2047
  int t = blk & 127, b = blk >> 7;
  int tid = threadIdx.x;
  int wav = tid >> 6, lane = tid & 63;
  __shared__ float xs[64][10];
  __shared__ float As[64][65];
  __shared__ float ys[64][8];
  __shared__ float invr[64];
  __shared__ float Wcs[64][8], Wss[64][8];
  __shared__ float bcs[64], bss[64];

  for (int idx = tid; idx < 512; idx += 256){
    int n = idx >> 3, d = idx & 7;
    xs[n][d]  = x[((size_t)(b*64 + n)*128 + t)*8 + d];
    Wcs[n][d] = Wc[idx];
    Wss[n][d] = Ws[idx];
  }
  if (tid < 64){ bcs[tid] = bc[tid]; bss[tid] = bs[tid]; }
  __syncthreads();

  // pairwise inverse distances (diag = 0); fused row-sum via wave reduce.
  // wave `wav` handles row m = 4*i + wav, lane = column n.
  #pragma unroll 4
  for (int i = 0; i < 16; i++){
    int m = (i << 2) | wav;
    int n = lane;
    float d2 = 0.f;
    #pragma unroll
    for (int d = 0; d < 8; d++){ float df = xs[m][d] - xs[n][d]; d2 += df*df; }
    float a = (m == n) ? 0.f : __frsqrt_rn(d2);   // 1/(sqrt(d2)+1e-20) ~= rsqrt
    As[m][n] = a;
    float s = a;
    #pragma unroll
    for (int off = 32; off >= 1; off >>= 1) s += __shfl_xor(s, off, 64);
    if (n == 0) invr[m] = rcp_(fmaxf(s, 1e-12f));
  }
  __syncthreads();

  // y = rownorm(A) @ x
  for (int idx = tid; idx < 512; idx += 256){
    int s = idx >> 3, d = idx & 7;
    float acc = 0.f;
    #pragma unroll
    for (int m = 0; m < 64; m++) acc += As[s][m]*xs[m][d];
    ys[s][d] = acc * invr[s];
  }
  __syncthreads();

  // outputs: f<64 skip-proj of x, f>=64 proj of y; SELU; half8 vector stores
  int n = tid >> 2, q = tid & 3;
  size_t obase = ((size_t)t*1024 + (size_t)b*64 + n)*128 + q*32;
  #pragma unroll
  for (int c8 = 0; c8 < 4; c8++){
    half8 pack;
    #pragma unroll
    for (int jj = 0; jj < 8; jj++){
      int f = q*32 + c8*8 + jj;
      const float* Wrow = (f < 64) ? &Wss[f][0] : &Wcs[f-64][0];
      const float* xv   = (f < 64) ? &xs[n][0]  : &ys[n][0];
      float v = (f < 64) ? bss[f] : bcs[f-64];
      #pragma unroll
      for (int d = 0; d < 8; d++) v = fmaf(xv[d], Wrow[d], v);
      v = (v > 0.f) ? 1.0507009873554805f*v
                    : 1.7580993408473766f*(__expf(v) - 1.0f);  // scale*alpha
      pack[jj] = (_Float16)v;
    }
    *(half8*)(feat + obase + c8*8) = pack;
  }
}

// ---------------------------------------------------------------------------
// Kernel 3: persistent LSTM. 64 blocks x 512 thr (8 waves). Block owns samples
// blk*16..+15. Weights (both GEMMs, K=256) live in VGPRs as B-fragments.
// Wave w owns gate columns j = 16w..16w+15 for all 4 gates -> in-register cell.
// Double-buffered h in LDS -> ONE raw s_barrier per step; feat prefetch stays
// in flight across the barrier (no vmcnt(0) drain -> latency hidden).
// ---------------------------------------------------------------------------
__global__ __launch_bounds__(512, 2) void lstm_kernel(
    const _Float16* __restrict__ wfrag, const _Float16* __restrict__ feat,
    const float* __restrict__ b_ih, const float* __restrict__ b_hh,
    float* __restrict__ out){
  int tid = threadIdx.x;
  int w = tid >> 6, l = tid & 63;
  int blk = blockIdx.x;            // 0..63
  int row = l & 15, kq = l >> 4;
  __shared__ _Float16 h_lds[2][16*136];  // [parity][sample][hidden], stride 136

  // load this wave's 32 B-fragments (coalesced: lane-contiguous layout)
  half8 bf[32];
  const _Float16* wb = wfrag + (size_t)w*(32*64*8);
  #pragma unroll
  for (int i = 0; i < 32; i++)
    bf[i] = *(const half8*)(wb + (size_t)(i*64 + l)*8);

  float bias[4];
  #pragma unroll
  for (int cti = 0; cti < 4; cti++){
    int j = 16*w + 128*cti + row;
    bias[cti] = b_ih[j] + b_hh[j];
  }

  for (int idx = tid; idx < 16*136; idx += 512) h_lds[0][idx] = (_Float16)0.f;

  float cc[4] = {0.f, 0.f, 0.f, 0.f};

  const size_t sbase = ((size_t)blk*16 + row)*128 + 8*kq;  // per-lane feat base
  half8 xa[4];
  #pragma unroll
  for (int kk = 0; kk < 4; kk++)
    xa[kk] = *(const half8*)(feat + sbase + 32*kk);        // t = 0
  __syncthreads();   // once: h0 init + weight frags visible

  const int hoff = row*136 + 8*kq;

  for (int t = 0; t < 128; ++t){
    int p = t & 1;

    // prefetch next step's x fragments (stays in flight across the barrier)
    half8 xn[4];
    size_t nb = (size_t)((t < 127) ? t + 1 : 127)*131072 + sbase;
    #pragma unroll
    for (int kk = 0; kk < 4; kk++)
      xn[kk] = *(const half8*)(feat + nb + 32*kk);

    // issue h reads early so LDS latency hides under the x-MFMAs
    half8 ha[4];
    #pragma unroll
    for (int kk = 0; kk < 4; kk++)
      ha[kk] = *(const half8*)(&h_lds[p][hoff + 32*kk]);

    f32x4 acc[4];
    #pragma unroll
    for (int c4 = 0; c4 < 4; c4++)
      acc[c4] = (f32x4){bias[c4], bias[c4], bias[c4], bias[c4]};

    #pragma unroll
    for (int kk = 0; kk < 4; kk++){
      #pragma unroll
      for (int cti = 0; cti < 4; cti++)
        acc[cti] = __builtin_amdgcn_mfma_f32_16x16x32_f16(xa[kk], bf[kk*4 + cti], acc[cti], 0, 0, 0);
    }
    #pragma unroll
    for (int kk = 0; kk < 4; kk++){
      #pragma unroll
      for (int cti = 0; cti < 4; cti++)
        acc[cti] = __builtin_amdgcn_mfma_f32_16x16x32_f16(ha[kk], bf[(4 + kk)*4 + cti], acc[cti], 0, 0, 0);
    }

    // in-register cell update: lane holds i,f,g,o for (s = 4*kq+e, j = 16w+row)
    #pragma unroll
    for (int e = 0; e < 4; e++){
      float gi = acc[0][e], gf = acc[1][e], gg = acc[2][e], go = acc[3][e];
      float c = fmaf(sigmoidf_(gf), cc[e], sigmoidf_(gi)*tanhf_(gg));
      cc[e] = c;
      float h = sigmoidf_(go)*tanhf_(c);
      h_lds[p^1][(4*kq + e)*136 + 16*w + row] = (_Float16)h;
      if (t == 127)
        out[((size_t)blk*16 + 4*kq + e)*128 + 16*w + row] = h;
    }

    // ONE barrier per step: drain LDS only; global prefetch stays outstanding
    asm volatile("s_waitcnt lgkmcnt(0)" ::: "memory");
    __builtin_amdgcn_s_barrier();

    #pragma unroll
    for (int kk = 0; kk < 4; kk++) xa[kk] = xn[kk];
  }
}

// ---------------------------------------------------------------------------
extern "C" void kernel_launch(void* const* d_in, const int* in_sizes, int n_in,
                              void* d_out, int out_size, void* d_ws, size_t ws_size,
                              hipStream_t stream) {
  const float* x    = (const float*)d_in[0];
  // d_in[1] rel_rec, d_in[2] rel_send: fully-connected structure is fixed; unused
  const float* Wc   = (const float*)d_in[3];
  const float* bc   = (const float*)d_in[4];
  const float* Ws   = (const float*)d_in[5];
  const float* bs   = (const float*)d_in[6];
  const float* W_ih = (const float*)d_in[7];
  const float* W_hh = (const float*)d_in[8];
  const float* b_ih = (const float*)d_in[9];
  const float* b_hh = (const float*)d_in[10];
  float* out = (float*)d_out;

  // ws layout: [0,256KB) weight fragments f16; [256KB, +33.5MB) feat f16
  _Float16* wfrag = (_Float16*)d_ws;
  _Float16* feat  = (_Float16*)((char*)d_ws + 262144);

  prep_kernel<<<64, 256, 0, stream>>>(W_ih, W_hh, wfrag);
  gcn_kernel<<<2048, 256, 0, stream>>>(x, Wc, bc, Ws, bs, feat);
  lstm_kernel<<<64, 512, 0, stream>>>(wfrag, feat, b_ih, b_hh, out);
}

// Round 3
// 171.684 us; speedup vs baseline: 1.7766x; 1.0471x over previous
//
#include <hip/hip_runtime.h>
#include <hip/hip_bf16.h>

// Problem constants (fixed by setup_inputs)
// B=16, N=64, T=128, D=8, N_EMB=64, N_H=128, BN=1024, F_in=128, gates=512

typedef _Float16 half8 __attribute__((ext_vector_type(8)));
typedef float f32x4 __attribute__((ext_vector_type(4)));

__device__ __forceinline__ float rcp_(float x){ return __builtin_amdgcn_rcpf(x); }
__device__ __forceinline__ float sigmoidf_(float x){ return rcp_(1.0f + __expf(-x)); }
__device__ __forceinline__ float tanhf_(float x){ return fmaf(-2.0f, rcp_(1.0f + __expf(2.0f*x)), 1.0f); }

// ---------------------------------------------------------------------------
// Kernel 1: repack W_ih (512x128) and W_hh (512x128) into f16 MFMA B-fragment
// order. Layout: wfrag[w][i][lane][e], i = src*16 + kk*4 + cti  (32 frags/wave)
//   j = 16*w + 128*cti + (lane&15)      (gate column; cti IS the gate index)
//   k = 32*kk + 8*(lane>>4) + e         (K position within src block)
// ---------------------------------------------------------------------------
__global__ __launch_bounds__(256) void prep_kernel(const float* __restrict__ W_ih,
                                                   const float* __restrict__ W_hh,
                                                   _Float16* __restrict__ wfrag){
  int gid = blockIdx.x*256 + threadIdx.x;   // [0, 16384)
  int w    = gid >> 11;        // 0..7
  int i    = (gid >> 6) & 31;  // 0..31
  int lane = gid & 63;
  int src = i >> 4, kk = (i >> 2) & 3, cti = i & 3;
  int j = 16*w + 128*cti + (lane & 15);
  int kbase = 32*kk + 8*(lane >> 4);
  const float* W = src ? W_hh : W_ih;
  _Float16* dst = wfrag + (size_t)(((w*32 + i)*64 + lane) * 8);
  #pragma unroll
  for (int e = 0; e < 8; e++) dst[e] = (_Float16)W[j*128 + kbase + e];
}

// ---------------------------------------------------------------------------
// Kernel 2: GCN. One block per (b,t). Writes feat[t][b*64+n][f] as f16.
// ---------------------------------------------------------------------------
__global__ __launch_bounds__(256) void gcn_kernel(const float* __restrict__ x,
    const float* __restrict__ Wc, const float* __restrict__ bc,
    const float* __restrict__ Ws, const float* __restrict__ bs,
    _Float16* __restrict__ feat){
  int blk = blockIdx.x;          // 0..2047
  int t = blk & 127, b = blk >> 7;
  int tid = threadIdx.x;
  int wav = tid >> 6, lane = tid & 63;
  __shared__ float xs[64][10];
  __shared__ float As[64][65];
  __shared__ float ys[64][8];
  __shared__ float invr[64];
  __shared__ float Wcs[64][8], Wss[64][8];
  __shared__ float bcs[64], bss[64];

  for (int idx = tid; idx < 512; idx += 256){
    int n = idx >> 3, d = idx & 7;
    xs[n][d]  = x[((size_t)(b*64 + n)*128 + t)*8 + d];
    Wcs[n][d] = Wc[idx];
    Wss[n][d] = Ws[idx];
  }
  if (tid < 64){ bcs[tid] = bc[tid]; bss[tid] = bs[tid]; }
  __syncthreads();

  // pairwise inverse distances (diag = 0); fused row-sum via wave reduce.
  #pragma unroll 4
  for (int i = 0; i < 16; i++){
    int m = (i << 2) | wav;
    int n = lane;
    float d2 = 0.f;
    #pragma unroll
    for (int d = 0; d < 8; d++){ float df = xs[m][d] - xs[n][d]; d2 += df*df; }
    float a = (m == n) ? 0.f : __frsqrt_rn(d2);
    As[m][n] = a;
    float s = a;
    #pragma unroll
    for (int off = 32; off >= 1; off >>= 1) s += __shfl_xor(s, off, 64);
    if (n == 0) invr[m] = rcp_(fmaxf(s, 1e-12f));
  }
  __syncthreads();

  // y = rownorm(A) @ x
  for (int idx = tid; idx < 512; idx += 256){
    int s = idx >> 3, d = idx & 7;
    float acc = 0.f;
    #pragma unroll
    for (int m = 0; m < 64; m++) acc += As[s][m]*xs[m][d];
    ys[s][d] = acc * invr[s];
  }
  __syncthreads();

  // outputs: f<64 skip-proj of x, f>=64 proj of y; SELU; half8 vector stores
  int n = tid >> 2, q = tid & 3;
  size_t obase = ((size_t)t*1024 + (size_t)b*64 + n)*128 + q*32;
  #pragma unroll
  for (int c8 = 0; c8 < 4; c8++){
    half8 pack;
    #pragma unroll
    for (int jj = 0; jj < 8; jj++){
      int f = q*32 + c8*8 + jj;
      const float* Wrow = (f < 64) ? &Wss[f][0] : &Wcs[f-64][0];
      const float* xv   = (f < 64) ? &xs[n][0]  : &ys[n][0];
      float v = (f < 64) ? bss[f] : bcs[f-64];
      #pragma unroll
      for (int d = 0; d < 8; d++) v = fmaf(xv[d], Wrow[d], v);
      v = (v > 0.f) ? 1.0507009873554805f*v
                    : 1.7580993408473766f*(__expf(v) - 1.0f);
      pack[jj] = (_Float16)v;
    }
    *(half8*)(feat + obase + c8*8) = pack;
  }
}

// ---------------------------------------------------------------------------
// Kernel 3: persistent LSTM. 128 blocks x 512 thr (8 waves). Block owns 8
// samples (blk*8..+7); MFMA M=16 rows 8..15 are clamped duplicates. After the
// GEMMs, e=2,3 gate values are shuffled to the high 32 lanes so every lane
// runs the cell update for exactly 2 (sample,hidden) pairs -> trans-pipe work
// per wave halves vs the 16-sample version, and 2x the CUs are active.
// One raw s_barrier per step; x fragments prefetched 2 steps ahead.
// ---------------------------------------------------------------------------
__global__ __launch_bounds__(512, 2) void lstm_kernel(
    const _Float16* __restrict__ wfrag, const _Float16* __restrict__ feat,
    const float* __restrict__ b_ih, const float* __restrict__ b_hh,
    float* __restrict__ out){
  int tid = threadIdx.x;
  int w = tid >> 6, l = tid & 63;
  int blk = blockIdx.x;            // 0..127
  int r  = l & 15;                 // A-frag row / C-frag col
  int kq = l >> 4;                 // 0..3
  bool hi = kq >= 2;
  int sbq = hi ? 4*kq - 6 : 4*kq;  // base sample for this lane's 2 pairs
  __shared__ _Float16 h_lds[2][8*136 + 8];

  // this wave's 32 B-fragments (lane-contiguous -> coalesced)
  half8 bf[32];
  const _Float16* wb = wfrag + (size_t)w*(32*64*8);
  #pragma unroll
  for (int i = 0; i < 32; i++)
    bf[i] = *(const half8*)(wb + (size_t)(i*64 + l)*8);

  float bias[4];
  #pragma unroll
  for (int cti = 0; cti < 4; cti++){
    int j = 16*w + 128*cti + r;
    bias[cti] = b_ih[j] + b_hh[j];
  }

  for (int idx = tid; idx < 8*136; idx += 512) h_lds[0][idx] = (_Float16)0.f;

  float cc[2] = {0.f, 0.f};
  float hlast[2];

  const size_t sbase = ((size_t)(blk*8 + (r & 7)))*128 + 8*kq;
  const int hoff = (r & 7)*136 + 8*kq;

  half8 xa[4], xb[4];
  #pragma unroll
  for (int kk = 0; kk < 4; kk++){
    xa[kk] = *(const half8*)(feat + sbase + 32*kk);            // t = 0
    xb[kk] = *(const half8*)(feat + 131072 + sbase + 32*kk);   // t = 1
  }
  __syncthreads();   // h0 init visible

#define STEP(T, XU, XL, PR, PW)                                               \
  {                                                                           \
    f32x4 acc[4];                                                             \
    _Pragma("unroll")                                                         \
    for (int c4 = 0; c4 < 4; c4++)                                            \
      acc[c4] = (f32x4){bias[c4], bias[c4], bias[c4], bias[c4]};              \
    _Pragma("unroll")                                                         \
    for (int kk = 0; kk < 4; kk++){                                           \
      _Pragma("unroll")                                                       \
      for (int cti = 0; cti < 4; cti++)                                       \
        acc[cti] = __builtin_amdgcn_mfma_f32_16x16x32_f16(XU[kk], bf[kk*4 + cti], acc[cti], 0, 0, 0); \
    }                                                                         \
    { /* reload XU with feat[XL] (2 steps ahead; stays in flight ~1 step) */  \
      size_t nb = (size_t)(XL)*131072 + sbase;                                \
      _Pragma("unroll")                                                       \
      for (int kk = 0; kk < 4; kk++)                                          \
        XU[kk] = *(const half8*)(feat + nb + 32*kk);                          \
    }                                                                         \
    half8 ha[4];                                                              \
    _Pragma("unroll")                                                         \
    for (int kk = 0; kk < 4; kk++)                                            \
      ha[kk] = *(const half8*)(&h_lds[PR][hoff + 32*kk]);                     \
    _Pragma("unroll")                                                         \
    for (int kk = 0; kk < 4; kk++){                                           \
      _Pragma("unroll")                                                       \
      for (int cti = 0; cti < 4; cti++)                                       \
        acc[cti] = __builtin_amdgcn_mfma_f32_16x16x32_f16(ha[kk], bf[(4+kk)*4 + cti], acc[cti], 0, 0, 0); \
    }                                                                         \
    float gv[4][2];                                                           \
    _Pragma("unroll")                                                         \
    for (int cti = 0; cti < 4; cti++){                                        \
      _Pragma("unroll")                                                       \
      for (int p2 = 0; p2 < 2; p2++){                                         \
        float sw = __shfl_xor(acc[cti][2 + p2], 32, 64);                      \
        gv[cti][p2] = hi ? sw : acc[cti][p2];                                 \
      }                                                                       \
    }                                                                         \
    _Pragma("unroll")                                                         \
    for (int p2 = 0; p2 < 2; p2++){                                           \
      float c = fmaf(sigmoidf_(gv[1][p2]), cc[p2],                            \
                     sigmoidf_(gv[0][p2])*tanhf_(gv[2][p2]));                 \
      cc[p2] = c;                                                             \
      float h = sigmoidf_(gv[3][p2])*tanhf_(c);                               \
      h_lds[PW][(sbq + p2)*136 + 16*w + r] = (_Float16)h;                     \
      if ((T) == 127) hlast[p2] = h;                                          \
    }                                                                         \
    asm volatile("s_waitcnt lgkmcnt(0)" ::: "memory");                        \
    __builtin_amdgcn_s_barrier();                                             \
  }

  for (int it = 0; it < 64; ++it){
    int t0 = 2*it, t1 = 2*it + 1;
    int l0 = (t0 + 2 > 127) ? 127 : t0 + 2;
    int l1 = (t1 + 2 > 127) ? 127 : t1 + 2;
    STEP(t0, xa, l0, 0, 1)
    STEP(t1, xb, l1, 1, 0)
  }
#undef STEP

  #pragma unroll
  for (int p2 = 0; p2 < 2; p2++)
    out[((size_t)blk*8 + sbq + p2)*128 + 16*w + r] = hlast[p2];
}

// ---------------------------------------------------------------------------
extern "C" void kernel_launch(void* const* d_in, const int* in_sizes, int n_in,
                              void* d_out, int out_size, void* d_ws, size_t ws_size,
                              hipStream_t stream) {
  const float* x    = (const float*)d_in[0];
  const float* Wc   = (const float*)d_in[3];
  const float* bc   = (const float*)d_in[4];
  const float* Ws   = (const float*)d_in[5];
  const float* bs   = (const float*)d_in[6];
  const float* W_ih = (const float*)d_in[7];
  const float* W_hh = (const float*)d_in[8];
  const float* b_ih = (const float*)d_in[9];
  const float* b_hh = (const float*)d_in[10];
  float* out = (float*)d_out;

  _Float16* wfrag = (_Float16*)d_ws;
  _Float16* feat  = (_Float16*)((char*)d_ws + 262144);

  prep_kernel<<<64, 256, 0, stream>>>(W_ih, W_hh, wfrag);
  gcn_kernel<<<2048, 256, 0, stream>>>(x, Wc, bc, Ws, bs, feat);
  lstm_kernel<<<128, 512, 0, stream>>>(wfrag, feat, b_ih, b_hh, out);
}

// Round 4
// 145.935 us; speedup vs baseline: 2.0901x; 1.1764x over previous
//
#include <hip/hip_runtime.h>
#include <hip/hip_bf16.h>

// Problem constants: B=16, N=64, T=128, D=8, N_EMB=64, N_H=128, BN=1024,
// F_in=128, gates=512.

typedef _Float16 half8 __attribute__((ext_vector_type(8)));
typedef _Float16 half4 __attribute__((ext_vector_type(4)));
typedef float f32x4 __attribute__((ext_vector_type(4)));

__device__ __forceinline__ float rcp_(float x){ return __builtin_amdgcn_rcpf(x); }
__device__ __forceinline__ float sigmoidf_(float x){ return rcp_(1.0f + __expf(-x)); }
__device__ __forceinline__ float tanhf_(float x){ return fmaf(-2.0f, rcp_(1.0f + __expf(2.0f*x)), 1.0f); }

// ---------------------------------------------------------------------------
// Kernel 1: repack W_ih (512x128) and W_hh (512x128) into f16 MFMA B-fragment
// order. wfrag[w][i][lane][e], i = src*16 + kk*4 + cti;
//   j = 16*w + 128*cti + (lane&15); k = 32*kk + 8*(lane>>4) + e
// ---------------------------------------------------------------------------
__global__ __launch_bounds__(256) void prep_kernel(const float* __restrict__ W_ih,
                                                   const float* __restrict__ W_hh,
                                                   _Float16* __restrict__ wfrag){
  int gid = blockIdx.x*256 + threadIdx.x;   // [0, 16384)
  int w    = gid >> 11;
  int i    = (gid >> 6) & 31;
  int lane = gid & 63;
  int src = i >> 4, kk = (i >> 2) & 3, cti = i & 3;
  int j = 16*w + 128*cti + (lane & 15);
  int kbase = 32*kk + 8*(lane >> 4);
  const float* W = src ? W_hh : W_ih;
  _Float16* dst = wfrag + (size_t)(((w*32 + i)*64 + lane) * 8);
  #pragma unroll
  for (int e = 0; e < 8; e++) dst[e] = (_Float16)W[j*128 + kbase + e];
}

// ---------------------------------------------------------------------------
// Kernel 2: GCN (unchanged). One block per (b,t). feat[t][b*64+n][f] f16.
// ---------------------------------------------------------------------------
__global__ __launch_bounds__(256) void gcn_kernel(const float* __restrict__ x,
    const float* __restrict__ Wc, const float* __restrict__ bc,
    const float* __restrict__ Ws, const float* __restrict__ bs,
    _Float16* __restrict__ feat){
  int blk = blockIdx.x;          // 0..2047
  int t = blk & 127, b = blk >> 7;
  int tid = threadIdx.x;
  int wav = tid >> 6, lane = tid & 63;
  __shared__ float xs[64][10];
  __shared__ float As[64][65];
  __shared__ float ys[64][8];
  __shared__ float invr[64];
  __shared__ float Wcs[64][8], Wss[64][8];
  __shared__ float bcs[64], bss[64];

  for (int idx = tid; idx < 512; idx += 256){
    int n = idx >> 3, d = idx & 7;
    xs[n][d]  = x[((size_t)(b*64 + n)*128 + t)*8 + d];
    Wcs[n][d] = Wc[idx];
    Wss[n][d] = Ws[idx];
  }
  if (tid < 64){ bcs[tid] = bc[tid]; bss[tid] = bs[tid]; }
  __syncthreads();

  #pragma unroll 4
  for (int i = 0; i < 16; i++){
    int m = (i << 2) | wav;
    int n = lane;
    float d2 = 0.f;
    #pragma unroll
    for (int d = 0; d < 8; d++){ float df = xs[m][d] - xs[n][d]; d2 += df*df; }
    float a = (m == n) ? 0.f : __frsqrt_rn(d2);
    As[m][n] = a;
    float s = a;
    #pragma unroll
    for (int off = 32; off >= 1; off >>= 1) s += __shfl_xor(s, off, 64);
    if (n == 0) invr[m] = rcp_(fmaxf(s, 1e-12f));
  }
  __syncthreads();

  for (int idx = tid; idx < 512; idx += 256){
    int s = idx >> 3, d = idx & 7;
    float acc = 0.f;
    #pragma unroll
    for (int m = 0; m < 64; m++) acc += As[s][m]*xs[m][d];
    ys[s][d] = acc * invr[s];
  }
  __syncthreads();

  int n = tid >> 2, q = tid & 3;
  size_t obase = ((size_t)t*1024 + (size_t)b*64 + n)*128 + q*32;
  #pragma unroll
  for (int c8 = 0; c8 < 4; c8++){
    half8 pack;
    #pragma unroll
    for (int jj = 0; jj < 8; jj++){
      int f = q*32 + c8*8 + jj;
      const float* Wrow = (f < 64) ? &Wss[f][0] : &Wcs[f-64][0];
      const float* xv   = (f < 64) ? &xs[n][0]  : &ys[n][0];
      float v = (f < 64) ? bss[f] : bcs[f-64];
      #pragma unroll
      for (int d = 0; d < 8; d++) v = fmaf(xv[d], Wrow[d], v);
      v = (v > 0.f) ? 1.0507009873554805f*v
                    : 1.7580993408473766f*(__expf(v) - 1.0f);
      pack[jj] = (_Float16)v;
    }
    *(half8*)(feat + obase + c8*8) = pack;
  }
}

// ---------------------------------------------------------------------------
// Kernel 2b: precompute gates_x = feat @ W_ih^T + (b_ih + b_hh), stored f16 in
// lstm fragment layout: gx[t][blk256][w][lane][cti], lane = kq*16 + r,
// value = gates_x[sample = blk*4 + kq][j = 16*w + 128*cti + r].
// Block = (t, g): samples 64g..64g+63. 256 thr = 4 waves; wave v owns
// coltiles ct = 8v..8v+7  (w_l = ct&7, cti = v).
// ---------------------------------------------------------------------------
__global__ __launch_bounds__(256) void xgemm_kernel(
    const _Float16* __restrict__ wfrag, const _Float16* __restrict__ feat,
    const float* __restrict__ b_ih, const float* __restrict__ b_hh,
    _Float16* __restrict__ gx){
  int blk = blockIdx.x;            // 0..2047
  int t = blk >> 4, g = blk & 15;
  int tid = threadIdx.x;
  int v = tid >> 6, l = tid & 63;
  int r = l & 15, q = l >> 4;

  __shared__ _Float16 fs[64*136];      // feat tile, padded rows
  __shared__ _Float16 gxo[4*2048];     // one Mtile in output (lstm-frag) order

  // stage feat rows 64g..+63 (f16, coalesced 16B loads)
  #pragma unroll
  for (int i = 0; i < 4; i++){
    int flat = tid + 256*i;            // 0..1023
    int n = flat >> 4, c8 = flat & 15;
    half8 vd = *(const half8*)(feat + ((size_t)t*1024 + 64*g + n)*128 + c8*8);
    *(half8*)(fs + n*136 + c8*8) = vd;
  }

  // B fragments + bias for this wave's 8 coltiles
  half8 bfr[8][4];
  float bb[8];
  #pragma unroll
  for (int c = 0; c < 8; c++){
    #pragma unroll
    for (int kk = 0; kk < 4; kk++)
      bfr[c][kk] = *(const half8*)(wfrag + (size_t)(((c*32) + kk*4 + v)*64 + l)*8);
    int j = 128*v + 16*c + r;
    bb[c] = b_ih[j] + b_hh[j];
  }
  __syncthreads();

  for (int m = 0; m < 4; m++){
    half8 af[4];
    #pragma unroll
    for (int kk = 0; kk < 4; kk++)
      af[kk] = *(const half8*)(fs + (16*m + r)*136 + 32*kk + 8*q);
    #pragma unroll
    for (int c = 0; c < 8; c++){
      f32x4 acc = (f32x4){bb[c], bb[c], bb[c], bb[c]};
      #pragma unroll
      for (int kk = 0; kk < 4; kk++)
        acc = __builtin_amdgcn_mfma_f32_16x16x32_f16(af[kk], bfr[c][kk], acc, 0, 0, 0);
      // write into output order: off = q*2048 + c*256 + (e*16+r)*4 + v
      #pragma unroll
      for (int e = 0; e < 4; e++)
        gxo[q*2048 + c*256 + e*64 + 4*r + v] = (_Float16)acc[e];
    }
    __syncthreads();
    // contiguous LDS -> global: region (t, 16g+4m+q2) blocks, 2048 f16 each
    size_t mbase = ((size_t)t*256 + 16*g + 4*m)*2048;
    #pragma unroll
    for (int q2 = 0; q2 < 4; q2++){
      half8 pk = *(const half8*)(gxo + q2*2048 + tid*8);
      *(half8*)(gx + mbase + q2*2048 + tid*8) = pk;
    }
    __syncthreads();
  }
}

// ---------------------------------------------------------------------------
// Kernel 3: persistent LSTM v2. 256 blocks x 512 thr, 4 samples/block.
// Only the h-GEMM (K=128) is in the loop; x-gates preloaded from gx.
// Lane (kq,r) of wave w: acc[cti][e] = gates(sample e, j=16w+128cti+r);
// select e = kq -> one cell update per lane, no shuffles.
// ---------------------------------------------------------------------------
__global__ __launch_bounds__(512, 2) void lstm2_kernel(
    const _Float16* __restrict__ wfrag, const _Float16* __restrict__ gx,
    float* __restrict__ out){
  int tid = threadIdx.x;
  int w = tid >> 6, l = tid & 63;
  int blk = blockIdx.x;            // 0..255
  int r = l & 15, kq = l >> 4;
  __shared__ _Float16 h_lds[2][544];   // rows 0..3 stride 134 (bank spread)

  // W_hh B-fragments (i = 16 + kk*4 + cti)
  half8 bf[16];
  const _Float16* wb = wfrag + (size_t)w*(32*64*8);
  #pragma unroll
  for (int kk = 0; kk < 4; kk++)
    #pragma unroll
    for (int cti = 0; cti < 4; cti++)
      bf[kk*4 + cti] = *(const half8*)(wb + (size_t)((16 + kk*4 + cti)*64 + l)*8);

  for (int idx = tid; idx < 544; idx += 512){ h_lds[0][idx] = (_Float16)0.f; h_lds[1][idx] = (_Float16)0.f; }

  float cc = 0.f;
  float hlast = 0.f;

  const size_t gbase = ((size_t)blk*8 + w)*256 + l*4;   // f16 units; +t*524288
  half4 ga = *(const half4*)(gx + gbase);               // t = 0
  half4 gb = *(const half4*)(gx + 524288 + gbase);      // t = 1
  __syncthreads();

  const int habase = (r & 3)*134 + 8*kq;   // + 32*kk

#define STEP(T, GU, TL, PR, PW)                                               \
  {                                                                           \
    half8 ha[4];                                                              \
    _Pragma("unroll")                                                         \
    for (int kk = 0; kk < 4; kk++)                                            \
      ha[kk] = *(const half8*)(&h_lds[PR][habase + 32*kk]);                   \
    f32x4 acc[4];                                                             \
    _Pragma("unroll")                                                         \
    for (int cti = 0; cti < 4; cti++){                                        \
      float gv = (float)GU[cti];                                              \
      acc[cti] = (f32x4){gv, gv, gv, gv};                                     \
    }                                                                         \
    _Pragma("unroll")                                                         \
    for (int kk = 0; kk < 4; kk++){                                           \
      _Pragma("unroll")                                                       \
      for (int cti = 0; cti < 4; cti++)                                       \
        acc[cti] = __builtin_amdgcn_mfma_f32_16x16x32_f16(ha[kk], bf[kk*4 + cti], acc[cti], 0, 0, 0); \
    }                                                                         \
    GU = *(const half4*)(gx + (size_t)(TL)*524288 + gbase);                   \
    float gsel[4];                                                            \
    _Pragma("unroll")                                                         \
    for (int cti = 0; cti < 4; cti++){                                        \
      float s01 = (kq & 1) ? acc[cti][1] : acc[cti][0];                       \
      float s23 = (kq & 1) ? acc[cti][3] : acc[cti][2];                       \
      gsel[cti] = (kq & 2) ? s23 : s01;                                       \
    }                                                                         \
    float c = fmaf(sigmoidf_(gsel[1]), cc, sigmoidf_(gsel[0])*tanhf_(gsel[2])); \
    cc = c;                                                                   \
    float h = sigmoidf_(gsel[3])*tanhf_(c);                                   \
    h_lds[PW][kq*134 + 16*w + r] = (_Float16)h;                               \
    if ((T) == 127) hlast = h;                                                \
    asm volatile("s_waitcnt lgkmcnt(0)" ::: "memory");                        \
    __builtin_amdgcn_s_barrier();                                             \
  }

  for (int it = 0; it < 64; ++it){
    int t0 = 2*it, t1 = 2*it + 1;
    int l0 = (t0 + 2 > 127) ? 127 : t0 + 2;
    int l1 = (t1 + 2 > 127) ? 127 : t1 + 2;
    STEP(t0, ga, l0, 0, 1)
    STEP(t1, gb, l1, 1, 0)
  }
#undef STEP

  out[((size_t)blk*4 + kq)*128 + 16*w + r] = hlast;
}

// ---------------------------------------------------------------------------
// Fallback LSTM (round-3, in-loop x-GEMM) for small ws_size.
// ---------------------------------------------------------------------------
__global__ __launch_bounds__(512, 2) void lstm_kernel(
    const _Float16* __restrict__ wfrag, const _Float16* __restrict__ feat,
    const float* __restrict__ b_ih, const float* __restrict__ b_hh,
    float* __restrict__ out){
  int tid = threadIdx.x;
  int w = tid >> 6, l = tid & 63;
  int blk = blockIdx.x;
  int r  = l & 15;
  int kq = l >> 4;
  bool hi = kq >= 2;
  int sbq = hi ? 4*kq - 6 : 4*kq;
  __shared__ _Float16 h_lds[2][8*136 + 8];

  half8 bf[32];
  const _Float16* wb = wfrag + (size_t)w*(32*64*8);
  #pragma unroll
  for (int i = 0; i < 32; i++)
    bf[i] = *(const half8*)(wb + (size_t)(i*64 + l)*8);

  float bias[4];
  #pragma unroll
  for (int cti = 0; cti < 4; cti++){
    int j = 16*w + 128*cti + r;
    bias[cti] = b_ih[j] + b_hh[j];
  }

  for (int idx = tid; idx < 8*136; idx += 512) h_lds[0][idx] = (_Float16)0.f;

  float cc[2] = {0.f, 0.f};
  float hlast[2] = {0.f, 0.f};

  const size_t sbase = ((size_t)(blk*8 + (r & 7)))*128 + 8*kq;
  const int hoff = (r & 7)*136 + 8*kq;

  half8 xa[4], xb[4];
  #pragma unroll
  for (int kk = 0; kk < 4; kk++){
    xa[kk] = *(const half8*)(feat + sbase + 32*kk);
    xb[kk] = *(const half8*)(feat + 131072 + sbase + 32*kk);
  }
  __syncthreads();

#define STEP(T, XU, XL, PR, PW)                                               \
  {                                                                           \
    f32x4 acc[4];                                                             \
    _Pragma("unroll")                                                         \
    for (int c4 = 0; c4 < 4; c4++)                                            \
      acc[c4] = (f32x4){bias[c4], bias[c4], bias[c4], bias[c4]};              \
    _Pragma("unroll")                                                         \
    for (int kk = 0; kk < 4; kk++){                                           \
      _Pragma("unroll")                                                       \
      for (int cti = 0; cti < 4; cti++)                                       \
        acc[cti] = __builtin_amdgcn_mfma_f32_16x16x32_f16(XU[kk], bf[kk*4 + cti], acc[cti], 0, 0, 0); \
    }                                                                         \
    {                                                                         \
      size_t nb = (size_t)(XL)*131072 + sbase;                                \
      _Pragma("unroll")                                                       \
      for (int kk = 0; kk < 4; kk++)                                          \
        XU[kk] = *(const half8*)(feat + nb + 32*kk);                          \
    }                                                                         \
    half8 ha[4];                                                              \
    _Pragma("unroll")                                                         \
    for (int kk = 0; kk < 4; kk++)                                            \
      ha[kk] = *(const half8*)(&h_lds[PR][hoff + 32*kk]);                     \
    _Pragma("unroll")                                                         \
    for (int kk = 0; kk < 4; kk++){                                           \
      _Pragma("unroll")                                                       \
      for (int cti = 0; cti < 4; cti++)                                       \
        acc[cti] = __builtin_amdgcn_mfma_f32_16x16x32_f16(ha[kk], bf[(4+kk)*4 + cti], acc[cti], 0, 0, 0); \
    }                                                                         \
    float gv[4][2];                                                           \
    _Pragma("unroll")                                                         \
    for (int cti = 0; cti < 4; cti++){                                        \
      _Pragma("unroll")                                                       \
      for (int p2 = 0; p2 < 2; p2++){                                         \
        float sw = __shfl_xor(acc[cti][2 + p2], 32, 64);                      \
        gv[cti][p2] = hi ? sw : acc[cti][p2];                                 \
      }                                                                       \
    }                                                                         \
    _Pragma("unroll")                                                         \
    for (int p2 = 0; p2 < 2; p2++){                                           \
      float c = fmaf(sigmoidf_(gv[1][p2]), cc[p2],                            \
                     sigmoidf_(gv[0][p2])*tanhf_(gv[2][p2]));                 \
      cc[p2] = c;                                                             \
      float h = sigmoidf_(gv[3][p2])*tanhf_(c);                               \
      h_lds[PW][(sbq + p2)*136 + 16*w + r] = (_Float16)h;                     \
      if ((T) == 127) hlast[p2] = h;                                          \
    }                                                                         \
    asm volatile("s_waitcnt lgkmcnt(0)" ::: "memory");                        \
    __builtin_amdgcn_s_barrier();                                             \
  }

  for (int it = 0; it < 64; ++it){
    int t0 = 2*it, t1 = 2*it + 1;
    int l0 = (t0 + 2 > 127) ? 127 : t0 + 2;
    int l1 = (t1 + 2 > 127) ? 127 : t1 + 2;
    STEP(t0, xa, l0, 0, 1)
    STEP(t1, xb, l1, 1, 0)
  }
#undef STEP

  #pragma unroll
  for (int p2 = 0; p2 < 2; p2++)
    out[((size_t)blk*8 + sbq + p2)*128 + 16*w + r] = hlast[p2];
}

// ---------------------------------------------------------------------------
extern "C" void kernel_launch(void* const* d_in, const int* in_sizes, int n_in,
                              void* d_out, int out_size, void* d_ws, size_t ws_size,
                              hipStream_t stream) {
  const float* x    = (const float*)d_in[0];
  const float* Wc   = (const float*)d_in[3];
  const float* bc   = (const float*)d_in[4];
  const float* Ws   = (const float*)d_in[5];
  const float* bs   = (const float*)d_in[6];
  const float* W_ih = (const float*)d_in[7];
  const float* W_hh = (const float*)d_in[8];
  const float* b_ih = (const float*)d_in[9];
  const float* b_hh = (const float*)d_in[10];
  float* out = (float*)d_out;

  // ws: [0,256KB) wfrag f16 | [256KB, +33.5MB) feat f16 | [+134MB) gx f16
  _Float16* wfrag = (_Float16*)d_ws;
  _Float16* feat  = (_Float16*)((char*)d_ws + 262144);
  _Float16* gxbuf = (_Float16*)((char*)d_ws + 33816576);
  const size_t need = 33816576ull + 134217728ull;

  prep_kernel<<<64, 256, 0, stream>>>(W_ih, W_hh, wfrag);
  gcn_kernel<<<2048, 256, 0, stream>>>(x, Wc, bc, Ws, bs, feat);
  if (ws_size >= need) {
    xgemm_kernel<<<2048, 256, 0, stream>>>(wfrag, feat, b_ih, b_hh, gxbuf);
    lstm2_kernel<<<256, 512, 0, stream>>>(wfrag, gxbuf, out);
  } else {
    lstm_kernel<<<128, 512, 0, stream>>>(wfrag, feat, b_ih, b_hh, out);
  }
}

// Round 5
// 116.802 us; speedup vs baseline: 2.6114x; 1.2494x over previous
//
#include <hip/hip_runtime.h>
#include <hip/hip_bf16.h>

// Problem constants: B=16, N=64, T=128, D=8, N_EMB=64, N_H=128, BN=1024,
// F_in=128, gates=512.

typedef _Float16 half8 __attribute__((ext_vector_type(8)));
typedef float f32x4 __attribute__((ext_vector_type(4)));

__device__ __forceinline__ float rcp_(float x){ return __builtin_amdgcn_rcpf(x); }
__device__ __forceinline__ float sigmoidf_(float x){ return rcp_(1.0f + __expf(-x)); }
__device__ __forceinline__ float tanhf_(float x){ return fmaf(-2.0f, rcp_(1.0f + __expf(2.0f*x)), 1.0f); }

// ---------------------------------------------------------------------------
// Kernel 1: repack W_ih (512x128) and W_hh (512x128) into f16 MFMA B-fragment
// order. wfrag[w][i][lane][e], i = src*16 + kk*4 + cti;
//   j = 16*w + 128*cti + (lane&15); k = 32*kk + 8*(lane>>4) + e
// ---------------------------------------------------------------------------
__global__ __launch_bounds__(256) void prep_kernel(const float* __restrict__ W_ih,
                                                   const float* __restrict__ W_hh,
                                                   _Float16* __restrict__ wfrag){
  int gid = blockIdx.x*256 + threadIdx.x;   // [0, 16384)
  int w    = gid >> 11;
  int i    = (gid >> 6) & 31;
  int lane = gid & 63;
  int src = i >> 4, kk = (i >> 2) & 3, cti = i & 3;
  int j = 16*w + 128*cti + (lane & 15);
  int kbase = 32*kk + 8*(lane >> 4);
  const float* W = src ? W_hh : W_ih;
  _Float16* dst = wfrag + (size_t)(((w*32 + i)*64 + lane) * 8);
  #pragma unroll
  for (int e = 0; e < 8; e++) dst[e] = (_Float16)W[j*128 + kbase + e];
}

// ---------------------------------------------------------------------------
// Kernel 2: GCN v2 — one WAVE per (b,t) slice; 512 blocks x 256 thr.
// dist via readlane broadcast; rowsum via ones-column; A@x (K=64, 8 MFMA) and
// concat-proj+bias (K=32, 32 MFMA, block-diagonal W2 with bias row k=16).
// feat[t][b*64+n][f] f16.
// ---------------------------------------------------------------------------
__global__ __launch_bounds__(256) void gcn2_kernel(const float* __restrict__ x,
    const float* __restrict__ Wc, const float* __restrict__ bc,
    const float* __restrict__ Ws, const float* __restrict__ bs,
    _Float16* __restrict__ feat){
  __shared__ _Float16 W2[32*136];       // [k][f] block-diag: Ws | Wc | bias row
  __shared__ _Float16 As16[4][64*72];   // per-wave unnormalized w, padded
  __shared__ _Float16 zs16[4][64*40];   // per-wave z = [x | y | 1 | 0], padded

  int tid = threadIdx.x;
  int wav = tid >> 6, lane = tid & 63;
  int slice = blockIdx.x*4 + wav;       // 0..2047
  int b = slice >> 7, t = slice & 127;
  int c = lane & 15, kq = lane >> 4;

  // build W2 (all 256 threads)
  for (int idx = tid; idx < 32*136; idx += 256){
    int k = idx / 136, f = idx - k*136;
    float v = 0.f;
    if (f < 64){
      if (k < 8) v = Ws[f*8 + k];
      else if (k == 16) v = bs[f];
    } else if (f < 128){
      if (k >= 8 && k < 16) v = Wc[(f-64)*8 + (k-8)];
      else if (k == 16) v = bc[f-64];
    }
    W2[idx] = (_Float16)v;
  }

  _Float16* As_w = &As16[wav][0];
  _Float16* zs_w = &zs16[wav][0];

  // per-lane x row (f32 in regs), write z row: [x(0-7) | 1@8 | 1@16 | zeros]
  const float* xrow = x + ((size_t)(b*64 + lane)*128 + t)*8;
  float4 xlo = *(const float4*)xrow;
  float4 xhi = *(const float4*)(xrow + 4);
  float xr[8] = {xlo.x, xlo.y, xlo.z, xlo.w, xhi.x, xhi.y, xhi.z, xhi.w};
  {
    half8 hx;
    #pragma unroll
    for (int d = 0; d < 8; d++) hx[d] = (_Float16)xr[d];
    half8 h1 = (half8){(_Float16)1.f,0,0,0,0,0,0,0};
    half8 h0 = (half8){0,0,0,0,0,0,0,0};
    *(half8*)(zs_w + lane*40)      = hx;
    *(half8*)(zs_w + lane*40 + 8)  = h1;  // col8 = 1 (rowsum col), 9-15 = 0
    *(half8*)(zs_w + lane*40 + 16) = h1;  // col16 = 1 (bias row), 17-23 = 0
    *(half8*)(zs_w + lane*40 + 24) = h0;  // 24-31 = 0
  }

  // pairwise 1/dist: lane = col n; x-rows broadcast from regs via readlane
  #pragma unroll 4
  for (int m = 0; m < 64; m++){
    float d2 = 0.f;
    #pragma unroll
    for (int d = 0; d < 8; d++){
      float xm = __int_as_float(__builtin_amdgcn_readlane(__float_as_int(xr[d]), m));
      float df = xm - xr[d];
      d2 = fmaf(df, df, d2);
    }
    float wv = (m == lane) ? 0.f : __frsqrt_rn(d2);
    As_w[m*72 + lane] = (_Float16)wv;
  }

  __syncthreads();   // W2 visible

  // projection B-fragments (loop-invariant): wfr[nt][e] = W2[8kq+e][16nt+c]
  half8 wfr[8];
  #pragma unroll
  for (int nt = 0; nt < 8; nt++){
    half8 tmp;
    #pragma unroll
    for (int e = 0; e < 8; e++) tmp[e] = W2[(8*kq + e)*136 + 16*nt + c];
    wfr[nt] = tmp;
  }

  // A@x B-fragments: x_aug[k][n] (cols 0-7 = x, col8 = ones)
  half8 bx0, bx1;
  {
    half8 t0, t1;
    #pragma unroll
    for (int e = 0; e < 8; e++){
      t0[e] = zs_w[(8*kq + e)*40 + c];
      t1[e] = zs_w[(32 + 8*kq + e)*40 + c];
    }
    bx0 = t0; bx1 = t1;
  }

  const f32x4 zero4 = (f32x4){0.f,0.f,0.f,0.f};

  // A@x + row-normalize -> y into zs cols 8-15
  #pragma unroll
  for (int mt = 0; mt < 4; mt++){
    half8 aa0 = *(const half8*)(As_w + (16*mt + c)*72 + 8*kq);
    half8 aa1 = *(const half8*)(As_w + (16*mt + c)*72 + 32 + 8*kq);
    f32x4 cax = __builtin_amdgcn_mfma_f32_16x16x32_f16(aa0, bx0, zero4, 0,0,0);
    cax = __builtin_amdgcn_mfma_f32_16x16x32_f16(aa1, bx1, cax, 0,0,0);
    int bidx = ((lane & 48) | 8) << 2;   // pull rowsum from lane (kq*16+8)
    #pragma unroll
    for (int e = 0; e < 4; e++){
      float rs = __int_as_float(__builtin_amdgcn_ds_bpermute(bidx, __float_as_int(cax[e])));
      float yv = cax[e] * rcp_(fmaxf(rs, 1e-12f));
      if (c < 8) zs_w[(16*mt + 4*kq + e)*40 + 8 + c] = (_Float16)yv;
    }
  }

  // concat-projection (K=32: x|y|bias-ones) + SELU + f16 store
  #pragma unroll
  for (int mt = 0; mt < 4; mt++){
    half8 az = *(const half8*)(zs_w + (16*mt + c)*40 + 8*kq);
    #pragma unroll
    for (int nt = 0; nt < 8; nt++){
      f32x4 pc = __builtin_amdgcn_mfma_f32_16x16x32_f16(az, wfr[nt], zero4, 0,0,0);
      #pragma unroll
      for (int e = 0; e < 4; e++){
        float v = pc[e];
        v = (v > 0.f) ? 1.0507009873554805f*v
                      : 1.7580993408473766f*(__expf(v) - 1.0f);
        feat[((size_t)t*1024 + (size_t)b*64 + 16*mt + 4*kq + e)*128 + 16*nt + c] = (_Float16)v;
      }
    }
  }
}

// ---------------------------------------------------------------------------
// Kernel 3: persistent fused LSTM. 256 blocks x 512 thr, 4 samples/block.
// Per 4-step group, ONE M=16 tile (4 samples x 4 t-locals) computes the
// x-gates (16 MFMA/wave, bias folded via C-operand); double-buffered so
// gates(g+1) are built during group g. h-GEMM (16 MFMA) + in-register cell
// per step; 1 raw s_barrier/step; feat fragments prefetched 2 groups ahead.
// ---------------------------------------------------------------------------
__global__ __launch_bounds__(512, 2) void lstm3_kernel(
    const _Float16* __restrict__ wfrag, const _Float16* __restrict__ feat,
    const float* __restrict__ b_ih, const float* __restrict__ b_hh,
    float* __restrict__ out){
  int tid = threadIdx.x;
  int w = tid >> 6, l = tid & 63;
  int blk = blockIdx.x;            // 0..255
  int r = l & 15, kq = l >> 4;
  __shared__ _Float16 h_lds[2][544];   // [parity][sample*134 + hidden]

  half8 bf[32];
  const _Float16* wb = wfrag + (size_t)w*(32*64*8);
  #pragma unroll
  for (int i = 0; i < 32; i++)
    bf[i] = *(const half8*)(wb + (size_t)(i*64 + l)*8);

  f32x4 biasx4[4];
  #pragma unroll
  for (int cti = 0; cti < 4; cti++){
    int j = 16*w + 128*cti + r;
    float bv = b_ih[j] + b_hh[j];
    biasx4[cti] = (f32x4){bv, bv, bv, bv};
  }

  for (int idx = tid; idx < 544; idx += 512) h_lds[0][idx] = (_Float16)0.f;

  float cc = 0.f, hlast = 0.f;
  const f32x4 zero4 = (f32x4){0.f,0.f,0.f,0.f};

  // x-slab A rows: row = sample*4 + tl; lane (r,kq) covers row r, k=32kk+8kq+e
  const size_t arow_s = (size_t)(blk*4 + (r >> 2));
  const int atl = r & 3;
  const int habase = (r & 3)*134 + 8*kq;

  half8 afA[4], afB[4];
  f32x4 accxA[4], accxB[4];

#define LOADAF(AF, G) {                                                       \
    int gg = (G) > 31 ? 31 : (G);                                             \
    const _Float16* fb = feat + ((size_t)(4*gg + atl)*1024 + arow_s)*128 + 8*kq; \
    AF[0] = *(const half8*)(fb);                                              \
    AF[1] = *(const half8*)(fb + 32);                                         \
    AF[2] = *(const half8*)(fb + 64);                                         \
    AF[3] = *(const half8*)(fb + 96);                                         \
  }

  // prologue: gates(0) built directly; afB <- feat(1); afA <- feat(2)
  LOADAF(afA, 0)
  #pragma unroll
  for (int cti = 0; cti < 4; cti++)
    accxA[cti] = __builtin_amdgcn_mfma_f32_16x16x32_f16(afA[0], bf[cti], biasx4[cti], 0,0,0);
  #pragma unroll
  for (int kk = 1; kk < 4; kk++)
    #pragma unroll
    for (int cti = 0; cti < 4; cti++)
      accxA[cti] = __builtin_amdgcn_mfma_f32_16x16x32_f16(afA[kk], bf[kk*4+cti], accxA[cti], 0,0,0);
  LOADAF(afB, 1)
  LOADAF(afA, 2)
  __syncthreads();

#define SEL(A) ((kq & 2) ? ((kq & 1) ? A[3] : A[2]) : ((kq & 1) ? A[1] : A[0]))

#define STEP3(TL, ACCU, ACCB, AFB_, GN)                                       \
  {                                                                           \
    half8 ha[4];                                                              \
    _Pragma("unroll")                                                         \
    for (int kk = 0; kk < 4; kk++)                                            \
      ha[kk] = *(const half8*)(&h_lds[(TL)&1][habase + 32*kk]);               \
    f32x4 acc0, acc1, acc2, acc3;                                             \
    acc0 = __builtin_amdgcn_mfma_f32_16x16x32_f16(ha[0], bf[16], zero4, 0,0,0); \
    acc1 = __builtin_amdgcn_mfma_f32_16x16x32_f16(ha[0], bf[17], zero4, 0,0,0); \
    acc2 = __builtin_amdgcn_mfma_f32_16x16x32_f16(ha[0], bf[18], zero4, 0,0,0); \
    acc3 = __builtin_amdgcn_mfma_f32_16x16x32_f16(ha[0], bf[19], zero4, 0,0,0); \
    _Pragma("unroll")                                                         \
    for (int kk = 1; kk < 4; kk++){                                           \
      acc0 = __builtin_amdgcn_mfma_f32_16x16x32_f16(ha[kk], bf[16+kk*4+0], acc0, 0,0,0); \
      acc1 = __builtin_amdgcn_mfma_f32_16x16x32_f16(ha[kk], bf[16+kk*4+1], acc1, 0,0,0); \
      acc2 = __builtin_amdgcn_mfma_f32_16x16x32_f16(ha[kk], bf[16+kk*4+2], acc2, 0,0,0); \
      acc3 = __builtin_amdgcn_mfma_f32_16x16x32_f16(ha[kk], bf[16+kk*4+3], acc3, 0,0,0); \
    }                                                                         \
    _Pragma("unroll")                                                         \
    for (int cti = 0; cti < 4; cti++){                                        \
      if ((TL) == 0)                                                          \
        ACCB[cti] = __builtin_amdgcn_mfma_f32_16x16x32_f16(AFB_[0], bf[cti], biasx4[cti], 0,0,0); \
      else                                                                    \
        ACCB[cti] = __builtin_amdgcn_mfma_f32_16x16x32_f16(AFB_[(TL)], bf[(TL)*4+cti], ACCB[cti], 0,0,0); \
    }                                                                         \
    if ((TL) == 3) LOADAF(AFB_, GN)                                           \
    float g0_ = SEL(acc0) + ACCU[0][(TL)];                                    \
    float g1_ = SEL(acc1) + ACCU[1][(TL)];                                    \
    float g2_ = SEL(acc2) + ACCU[2][(TL)];                                    \
    float g3_ = SEL(acc3) + ACCU[3][(TL)];                                    \
    float c_ = fmaf(sigmoidf_(g1_), cc, sigmoidf_(g0_)*tanhf_(g2_));          \
    cc = c_;                                                                  \
    float h_ = sigmoidf_(g3_)*tanhf_(c_);                                     \
    h_lds[1-((TL)&1)][kq*134 + 16*w + r] = (_Float16)h_;                      \
    hlast = h_;                                                               \
    asm volatile("s_waitcnt lgkmcnt(0)" ::: "memory");                        \
    __builtin_amdgcn_s_barrier();                                             \
  }

  for (int i = 0; i < 16; ++i){
    STEP3(0, accxA, accxB, afB, 0)
    STEP3(1, accxA, accxB, afB, 0)
    STEP3(2, accxA, accxB, afB, 0)
    STEP3(3, accxA, accxB, afB, 2*i+3)
    STEP3(0, accxB, accxA, afA, 0)
    STEP3(1, accxB, accxA, afA, 0)
    STEP3(2, accxB, accxA, afA, 0)
    STEP3(3, accxB, accxA, afA, 2*i+4)
  }
#undef STEP3
#undef SEL
#undef LOADAF

  out[((size_t)blk*4 + kq)*128 + 16*w + r] = hlast;
}

// ---------------------------------------------------------------------------
extern "C" void kernel_launch(void* const* d_in, const int* in_sizes, int n_in,
                              void* d_out, int out_size, void* d_ws, size_t ws_size,
                              hipStream_t stream) {
  const float* x    = (const float*)d_in[0];
  const float* Wc   = (const float*)d_in[3];
  const float* bc   = (const float*)d_in[4];
  const float* Ws   = (const float*)d_in[5];
  const float* bs   = (const float*)d_in[6];
  const float* W_ih = (const float*)d_in[7];
  const float* W_hh = (const float*)d_in[8];
  const float* b_ih = (const float*)d_in[9];
  const float* b_hh = (const float*)d_in[10];
  float* out = (float*)d_out;

  // ws: [0,256KB) wfrag f16 | [256KB, +33.5MB) feat f16
  _Float16* wfrag = (_Float16*)d_ws;
  _Float16* feat  = (_Float16*)((char*)d_ws + 262144);

  prep_kernel<<<64, 256, 0, stream>>>(W_ih, W_hh, wfrag);
  gcn2_kernel<<<512, 256, 0, stream>>>(x, Wc, bc, Ws, bs, feat);
  lstm3_kernel<<<256, 512, 0, stream>>>(wfrag, feat, b_ih, b_hh, out);
}